// Round 23
// baseline (167.788 us; speedup 1.0000x reference)
//
#include <hip/hip_runtime.h>

#define N_NODES 50000
#define N_EDGES 800000
#define IN_C 128
#define HID_C 256
#define OUT_C 128
#define NBLK 196   // ceil(N_NODES / 256)
#define NPART 8    // XCD count; partition width = N_NODES/8 = 6250
#define NREP 8     // rank-counter replicas (contention /8)
#define REP_W (N_EDGES / NREP)  // 100000 edges per replica
#define EB 3125          // edge blocks
#define XCONV_BLKS 6250  // N_NODES*IN_C/4 / 256
#define WCONV_BLKS 64    // 16384 u32 / 256

typedef __attribute__((ext_vector_type(8))) short short8v;  // 8 bf16
typedef __attribute__((ext_vector_type(4))) float f32x4;

static __device__ __forceinline__ unsigned short f2bf(float f) {
  unsigned int u = __float_as_uint(f);
  unsigned int r = (u + 0x7fffu + ((u >> 16) & 1u)) >> 16;  // RNE
  return (unsigned short)r;
}
static __device__ __forceinline__ float bf2f(unsigned short h) {
  return __uint_as_float(((unsigned int)h) << 16);
}
// bf16 pair packing: u32 = bf(a) | bf(b)<<16  (natural k-order pairs)
static __device__ __forceinline__ unsigned int packBF2(float a, float b) {
  return (unsigned int)f2bf(a) | ((unsigned int)f2bf(b) << 16);
}

// ---------------------------------------------------------------------------
__global__ __launch_bounds__(256) void deg_zero_k(int* __restrict__ deg8) {
  const int i = blockIdx.x * 256 + threadIdx.x;
  if (i < NREP * N_NODES) deg8[i] = 0;
}

// ---------------------------------------------------------------------------
// MERGED kernel: blocks [0,EB) = edge conversion + REPLICATED dst histogram.
// Replica r = e/REP_W: rank-atomics contend 8x less per address. Pack
// edata[e].x = d | lrank<<16 | r<<29 (lrank < 8192 guaranteed, Poisson(2)).
// Blocks [EB,..) = x -> bf16, W1/W2 -> bf16-pair conversions.
// ---------------------------------------------------------------------------
__global__ __launch_bounds__(256) void convert_conv_k(
    const int* __restrict__ ei, uint2* __restrict__ edata, int* __restrict__ deg8,
    const float* __restrict__ x, unsigned int* __restrict__ xbf,
    const float* __restrict__ W1, unsigned int* __restrict__ w1bf,
    const float* __restrict__ W2, unsigned int* __restrict__ w2bf) {
  const int b = blockIdx.x;
  if (b < EB) {
    __shared__ int s_is64;
    if (threadIdx.x == 0) {
      int nz = 0;
#pragma unroll
      for (int k = 0; k < 64; ++k) nz |= ei[2 * k + 1];
      s_is64 = (nz == 0) ? 1 : 0;
    }
    __syncthreads();
    const int is64 = s_is64;
    const int e = b * 256 + threadIdx.x;
    if (e < N_EDGES) {
      int s, d;
      if (is64) {
        const uint2 sv = ((const uint2*)ei)[e];            // low word = src
        const uint2 dv = ((const uint2*)ei)[N_EDGES + e];  // low word = dst
        s = (int)sv.x;
        d = (int)dv.x;
      } else {
        s = ei[e];
        d = ei[N_EDGES + e];
      }
      const int rep = e / REP_W;  // 0..7
      const int lrank = atomicAdd(&deg8[rep * N_NODES + d], 1);
      const uint2 t = {(unsigned int)d | ((unsigned int)lrank << 16) |
                           ((unsigned int)rep << 29),
                       (unsigned int)s};
      edata[e] = t;
    }
  } else if (b < EB + XCONV_BLKS) {
    const int i = (b - EB) * 256 + threadIdx.x;  // over N*C/4 float4s
    const float4 f = *(const float4*)(x + (long)i * 4);
    uint2 u = {packBF2(f.x, f.y), packBF2(f.z, f.w)};
    *(uint2*)(xbf + (long)i * 2) = u;
  } else if (b < EB + XCONV_BLKS + WCONV_BLKS) {
    const int i = (b - EB - XCONV_BLKS) * 256 + threadIdx.x;  // u32 index
    const float2 f = *(const float2*)(W1 + (long)i * 2);
    w1bf[i] = packBF2(f.x, f.y);
  } else {
    const int i = (b - EB - XCONV_BLKS - WCONV_BLKS) * 256 + threadIdx.x;
    const float2 f = *(const float2*)(W2 + (long)i * 2);
    w2bf[i] = packBF2(f.x, f.y);
  }
}

// ---------------------------------------------------------------------------
// Parallel 3-phase exclusive scan over total degree (bsum / bscan / bfinal).
// bfinal also emits dinv and the per-replica offset table repoff[d*8+r].
// ---------------------------------------------------------------------------
__global__ __launch_bounds__(256) void bsum_k(const int* __restrict__ deg8,
                                              int* __restrict__ bsum) {
  const int i = blockIdx.x * 256 + threadIdx.x;
  int v = 0;
  if (i < N_NODES) {
#pragma unroll
    for (int r = 0; r < NREP; ++r) v += deg8[r * N_NODES + i];
  }
#pragma unroll
  for (int off = 32; off > 0; off >>= 1) v += __shfl_down(v, off, 64);
  __shared__ int ws[4];
  if ((threadIdx.x & 63) == 0) ws[threadIdx.x >> 6] = v;
  __syncthreads();
  if (threadIdx.x == 0) bsum[blockIdx.x] = ws[0] + ws[1] + ws[2] + ws[3];
}

__global__ __launch_bounds__(256) void bscan_k(const int* __restrict__ bsum,
                                               int* __restrict__ boff) {
  __shared__ int s[256];
  const int t = threadIdx.x;
  const int v = (t < NBLK) ? bsum[t] : 0;
  s[t] = v;
  __syncthreads();
  for (int off = 1; off < 256; off <<= 1) {
    const int tmp = (t >= off) ? s[t - off] : 0;
    __syncthreads();
    s[t] += tmp;
    __syncthreads();
  }
  if (t < NBLK) boff[t] = s[t] - v;
}

__global__ __launch_bounds__(256) void bfinal_k(const int* __restrict__ deg8,
                                                const int* __restrict__ boff,
                                                int* __restrict__ rowstart,
                                                float* __restrict__ dinv,
                                                int* __restrict__ repoff) {
  __shared__ int s[256];
  const int t = threadIdx.x;
  const int i = blockIdx.x * 256 + t;
  int dr[NREP];
  int dtot = 0;
  if (i < N_NODES) {
#pragma unroll
    for (int r = 0; r < NREP; ++r) {
      dr[r] = deg8[r * N_NODES + i];
      dtot += dr[r];
    }
  }
  s[t] = dtot;
  __syncthreads();
  for (int off = 1; off < 256; off <<= 1) {
    const int tmp = (t >= off) ? s[t - off] : 0;
    __syncthreads();
    s[t] += tmp;
    __syncthreads();
  }
  const int run = boff[blockIdx.x] + s[t] - dtot;
  if (i < N_NODES) {
    rowstart[i] = run;
    dinv[i] = rsqrtf((float)dtot + 1.0f);
    int acc = run;
#pragma unroll
    for (int r = 0; r < NREP; ++r) {
      repoff[i * NREP + r] = acc;
      acc += dr[r];
    }
    if (i == N_NODES - 1) rowstart[N_NODES] = run + dtot;
  }
}

// ---------------------------------------------------------------------------
// XCD-partitioned, atomic-free CSR fill: pos = repoff[d*8+rep] + lrank.
// Partition p = bx&7 => one dst-range per XCD (bucket lines coalesce in L2).
// ---------------------------------------------------------------------------
__global__ __launch_bounds__(256) void fill_csr_part_k(const uint2* __restrict__ edata,
                                                       const int* __restrict__ repoff,
                                                       int* __restrict__ csr_src) {
  const int p = blockIdx.x & 7;
  const int e = (blockIdx.x >> 3) * 256 + threadIdx.x;
  if (e < N_EDGES) {
    const uint2 t = edata[e];
    const int d = t.x & 0xffff;
    if (d / 6250 == p) {
      const int lrank = (t.x >> 16) & 0x1fff;
      const int rep = (int)(t.x >> 29);
      csr_src[repoff[d * NREP + rep] + lrank] = (int)t.y;
    }
  }
}

// ---------------------------------------------------------------------------
// FUSED both-layer GEMM, NT=64, W in plain bf16 (one MFMA per tile per ks):
//   GEMM1: h1 = relu(aggx @ W1^T + b1)   (K=128, M=256) -> LDS (bf16 packed)
//   GEMM2: h2 = h1 @ W2^T                (K=256, M=128) -> global bf16 packed
// aggx staged in LDS once; h1 never touches HBM.
// Swapped MFMA operand order (m89-verified): lane's 4 acc = 4 consecutive m
// for one n.
// ---------------------------------------------------------------------------
__global__ __launch_bounds__(256) void gemm_fused_k(
    const unsigned int* __restrict__ X,     // aggx bf16-packed [N][64]
    const unsigned int* __restrict__ W1BF,  // [256][64] bf16-pairs
    const float* __restrict__ b1,
    const unsigned int* __restrict__ W2BF,  // [128][128] bf16-pairs
    unsigned int* __restrict__ outBF) {     // h2 bf16-packed [N][64]
  constexpr int KP1 = 68;   // aggx LDS row stride (64 + 4 pad)
  constexpr int HP = 132;   // h1 LDS row stride (128 + 4 pad)
  __shared__ unsigned int xs[64 * KP1];   // 17.4 KB
  __shared__ unsigned int h1s[64 * HP];   // 33.8 KB

  const int tid = threadIdx.x;
  const int w = tid >> 6;
  const int l = tid & 63;
  const long nbase = (long)blockIdx.x * 64;
  const int kg = (l >> 4) * 8;
  const int lr = l & 15;
  const int mq0 = (l >> 4) * 4;

  // ---- Stage aggx tile: 64 rows x 64 u32 ----
#pragma unroll
  for (int i = 0; i < 4; ++i) {
    const int idx = (tid + i * 256) * 4;
    const int row = idx >> 6, col = idx & 63;
    long gr = nbase + row;
    if (gr > N_NODES - 1) gr = N_NODES - 1;  // clamp; final stores guarded
    const uint4 v = *(const uint4*)(X + gr * 64 + col);
    *(uint4*)(xs + row * KP1 + col) = v;
  }
  __syncthreads();

  // ---- GEMM1: wave w owns m in [w*64, w*64+64), K=128 ----
  {
    const int m0w = w * 64;
    f32x4 acc[4][4];
#pragma unroll
    for (int nt = 0; nt < 4; ++nt)
#pragma unroll
      for (int mt = 0; mt < 4; ++mt) acc[nt][mt] = {0.0f, 0.0f, 0.0f, 0.0f};

#pragma unroll
    for (int ks = 0; ks < 4; ++ks) {
      const int ko = ks * 32 + kg;  // bf16-element offset; /2 = u32 offset
      short8v wb[4];
#pragma unroll
      for (int mt = 0; mt < 4; ++mt)
        wb[mt] = *(const short8v*)(W1BF + (long)(m0w + mt * 16 + lr) * (IN_C / 2) +
                                   ko / 2);
#pragma unroll
      for (int nt = 0; nt < 4; ++nt) {
        const short8v xb = *(const short8v*)(xs + (nt * 16 + lr) * KP1 + ko / 2);
#pragma unroll
        for (int mt = 0; mt < 4; ++mt)
          acc[nt][mt] = __builtin_amdgcn_mfma_f32_16x16x32_bf16(wb[mt], xb,
                                                               acc[nt][mt], 0, 0, 0);
      }
    }

    // Epilogue 1: bias + relu -> packed bf16 into LDS h1s
#pragma unroll
    for (int nt = 0; nt < 4; ++nt) {
      const int nl = nt * 16 + lr;
#pragma unroll
      for (int mt = 0; mt < 4; ++mt) {
        const int mq = m0w + mt * 16 + mq0;
        const float4 bv = *(const float4*)(b1 + mq);
        const float v0 = fmaxf(acc[nt][mt][0] + bv.x, 0.0f);
        const float v1 = fmaxf(acc[nt][mt][1] + bv.y, 0.0f);
        const float v2 = fmaxf(acc[nt][mt][2] + bv.z, 0.0f);
        const float v3 = fmaxf(acc[nt][mt][3] + bv.w, 0.0f);
        uint2 o = {packBF2(v0, v1), packBF2(v2, v3)};
        *(uint2*)(h1s + nl * HP + mq / 2) = o;
      }
    }
  }
  __syncthreads();

  // ---- GEMM2: wave w owns m in [w*32, w*32+32), K=256 from LDS h1s ----
  {
    const int m0w = w * 32;
    f32x4 acc[4][2];
#pragma unroll
    for (int nt = 0; nt < 4; ++nt)
#pragma unroll
      for (int mt = 0; mt < 2; ++mt) acc[nt][mt] = {0.0f, 0.0f, 0.0f, 0.0f};

#pragma unroll
    for (int ks = 0; ks < 8; ++ks) {
      const int ko = ks * 32 + kg;
      short8v wb[2];
#pragma unroll
      for (int mt = 0; mt < 2; ++mt)
        wb[mt] = *(const short8v*)(W2BF + (long)(m0w + mt * 16 + lr) * (HID_C / 2) +
                                   ko / 2);
#pragma unroll
      for (int nt = 0; nt < 4; ++nt) {
        const short8v xb = *(const short8v*)(h1s + (nt * 16 + lr) * HP + ko / 2);
#pragma unroll
        for (int mt = 0; mt < 2; ++mt)
          acc[nt][mt] = __builtin_amdgcn_mfma_f32_16x16x32_bf16(wb[mt], xb,
                                                               acc[nt][mt], 0, 0, 0);
      }
    }

    // Epilogue 2: packed bf16 h2 to global
#pragma unroll
    for (int nt = 0; nt < 4; ++nt) {
      const long n = nbase + nt * 16 + lr;
      if (n < N_NODES) {
#pragma unroll
        for (int mt = 0; mt < 2; ++mt) {
          const int mq = m0w + mt * 16 + mq0;
          uint2 o = {packBF2(acc[nt][mt][0], acc[nt][mt][1]),
                     packBF2(acc[nt][mt][2], acc[nt][mt][3])};
          *(uint2*)(outBF + n * (OUT_C / 2) + mq / 2) = o;
        }
      }
    }
  }
}

// ---------------------------------------------------------------------------
// Gather-aggregate (one wave per destination node) over PACKED-BF16 rows.
// Lane reads 1 u32 = 2 channels per row. 8-edge unroll for MLP.
// OUT_BF: write packed bf16 u32 (feeds fused GEMM). Else fp32 (+bias) final.
// ---------------------------------------------------------------------------
template <int C, bool HAS_BIAS, bool OUT_BF>
__global__ __launch_bounds__(256) void gather_k(const int* __restrict__ rowstart,
                                                const int* __restrict__ csr_src,
                                                const float* __restrict__ dinv,
                                                const unsigned int* __restrict__ hbf,
                                                const float* __restrict__ bias,
                                                float* __restrict__ out,
                                                unsigned int* __restrict__ outBF) {
  const int v = (blockIdx.x * 256 + threadIdx.x) >> 6;
  if (v >= N_NODES) return;
  const int lane = threadIdx.x & 63;
  constexpr int CW = C / 2;  // u32 words per row
  const int rs = rowstart[v];
  const int re = rowstart[v + 1];
  const float dv = dinv[v];

  float a0 = 0.0f, a1 = 0.0f;

  int e = rs;
  for (; e + 7 < re; e += 8) {
    int s[8];
    float nn[8];
    unsigned int r[8];
#pragma unroll
    for (int j = 0; j < 8; ++j) s[j] = csr_src[e + j];
#pragma unroll
    for (int j = 0; j < 8; ++j) nn[j] = dv * dinv[s[j]];
#pragma unroll
    for (int j = 0; j < 8; ++j) r[j] = hbf[(long)s[j] * CW + lane];
#pragma unroll
    for (int j = 0; j < 8; ++j) {
      a0 += nn[j] * bf2f((unsigned short)r[j]);
      a1 += nn[j] * bf2f((unsigned short)(r[j] >> 16));
    }
  }
  for (; e + 3 < re; e += 4) {
    int s[4];
    float nn[4];
    unsigned int r[4];
#pragma unroll
    for (int j = 0; j < 4; ++j) s[j] = csr_src[e + j];
#pragma unroll
    for (int j = 0; j < 4; ++j) nn[j] = dv * dinv[s[j]];
#pragma unroll
    for (int j = 0; j < 4; ++j) r[j] = hbf[(long)s[j] * CW + lane];
#pragma unroll
    for (int j = 0; j < 4; ++j) {
      a0 += nn[j] * bf2f((unsigned short)r[j]);
      a1 += nn[j] * bf2f((unsigned short)(r[j] >> 16));
    }
  }
  for (; e < re; ++e) {
    const int s0 = csr_src[e];
    const float n0 = dv * dinv[s0];
    const unsigned int r0 = hbf[(long)s0 * CW + lane];
    a0 += n0 * bf2f((unsigned short)r0);
    a1 += n0 * bf2f((unsigned short)(r0 >> 16));
  }

  const float s2 = dv * dv;
  const unsigned int hv = hbf[(long)v * CW + lane];
  float o0 = s2 * bf2f((unsigned short)hv) + a0;
  float o1 = s2 * bf2f((unsigned short)(hv >> 16)) + a1;
  if (HAS_BIAS) {
    const float2 bv = *(const float2*)(bias + lane * 2);
    o0 += bv.x;
    o1 += bv.y;
  }
  if (OUT_BF) {
    outBF[(long)v * CW + lane] = packBF2(o0, o1);
  } else {
    const float2 o = {o0, o1};
    *(float2*)(out + (long)v * CW * 2 + lane * 2) = o;
  }
}

// ---------------------------------------------------------------------------
extern "C" void kernel_launch(void* const* d_in, const int* in_sizes, int n_in,
                              void* d_out, int out_size, void* d_ws, size_t ws_size,
                              hipStream_t stream) {
  (void)in_sizes; (void)n_in; (void)out_size; (void)ws_size;

  const float* x  = (const float*)d_in[0];
  const int*   ei = (const int*)d_in[1];
  const float* W1 = (const float*)d_in[2];
  const float* b1 = (const float*)d_in[3];
  const float* W2 = (const float*)d_in[4];
  const float* b2 = (const float*)d_in[5];
  float* out = (float*)d_out;

  // Workspace layout (bytes):
  char* ws = (char*)d_ws;
  uint2* edata    = (uint2*)(ws + 0);          //  6.4 MB {d|lrank<<16|rep<<29, src}
  int*   csr_src  = (int*)(ws + 6400000);      //  3.2 MB
  int*   deg8     = (int*)(ws + 9600000);      //  1.6 MB (8 replicas)
  int*   rowstart = (int*)(ws + 11200000);     //  0.2 MB (N+1)
  float* dinv     = (float*)(ws + 11400016);   //  0.2 MB
  int*   bsum     = (int*)(ws + 11600016);
  int*   boff     = (int*)(ws + 11601040);
  int*   repoff   = (int*)(ws + 11700000);     //  1.6 MB (N*8)
  unsigned int* w1bf   = (unsigned int*)(ws + 13400000);  // 65.5 KB
  unsigned int* w2bf   = (unsigned int*)(ws + 13500000);  // 65.5 KB
  unsigned int* aggxbf = (unsigned int*)(ws + 14000000);  // 12.8 MB (bf16 packed)
  unsigned int* h2bf   = (unsigned int*)(ws + 27000000);  // 12.8 MB (bf16 packed)
  unsigned int* xbf    = (unsigned int*)(ws + 91200000);  // 12.8 MB

  const int GB = (N_NODES + 3) / 4;  // gather: 1 node/wave

  // ---- Preproc: deg8 zero, merged edge-convert+histogram & conversions ----
  deg_zero_k<<<(NREP * N_NODES + 255) / 256, 256, 0, stream>>>(deg8);
  convert_conv_k<<<EB + XCONV_BLKS + 2 * WCONV_BLKS, 256, 0, stream>>>(
      ei, edata, deg8, x, xbf, W1, w1bf, W2, w2bf);
  bsum_k<<<NBLK, 256, 0, stream>>>(deg8, bsum);
  bscan_k<<<1, 256, 0, stream>>>(bsum, boff);
  bfinal_k<<<NBLK, 256, 0, stream>>>(deg8, boff, rowstart, dinv, repoff);
  fill_csr_part_k<<<EB * NPART, 256, 0, stream>>>(edata, repoff, csr_src);

  // ---- Layer 1 gather: aggx = agg(x_bf16) (bf16 out) ----
  gather_k<IN_C, false, true><<<GB, 256, 0, stream>>>(
      rowstart, csr_src, dinv, xbf, nullptr, nullptr, aggxbf);

  // ---- Fused GEMM1+GEMM2: h2 = relu(aggx@W1^T + b1) @ W2^T (h1 stays in LDS)
  gemm_fused_k<<<(N_NODES + 63) / 64, 256, 0, stream>>>(aggxbf, w1bf, b1, w2bf,
                                                        h2bf);

  // ---- Layer 2 gather: out = agg(h2_bf16) + b2 ----
  gather_k<OUT_C, true, false><<<GB, 256, 0, stream>>>(
      rowstart, csr_src, dinv, h2bf, b2, out, nullptr);
}